// Round 1
// baseline (354.319 us; speedup 1.0000x reference)
//
#include <hip/hip_runtime.h>

#define N_POINTS 8192
#define K_CENTERS 128
#define IFD 64
#define L1D 64
#define L2D 64
#define L3D 128
#define QS 4096  // max points per ball (observed max ~1.7K for N(0,1) coords)

typedef float vf16 __attribute__((ext_vector_type(16)));

#define LD4(p) (*(const float4*)(p))
// Param names must not collide with .x/.y/.z/.w member tokens.
#define FMA4(D_, O_, W_, V_)                       \
  D_[(O_) + 0] = fmaf(V_, (W_).x, D_[(O_) + 0]);   \
  D_[(O_) + 1] = fmaf(V_, (W_).y, D_[(O_) + 1]);   \
  D_[(O_) + 2] = fmaf(V_, (W_).z, D_[(O_) + 2]);   \
  D_[(O_) + 3] = fmaf(V_, (W_).w, D_[(O_) + 3]);

#define FMA16ROW(ACC_, PW_, HV_)                                    \
  {                                                                 \
    const float4 wa_ = LD4(PW_);                                    \
    const float4 wb_ = LD4((PW_) + 4);                              \
    const float4 wc_ = LD4((PW_) + 8);                              \
    const float4 wd_ = LD4((PW_) + 12);                             \
    FMA4(ACC_, 0, wa_, HV_)                                         \
    FMA4(ACC_, 4, wb_, HV_)                                         \
    FMA4(ACC_, 8, wc_, HV_)                                         \
    FMA4(ACC_, 12, wd_, HV_)                                        \
  }

#define SET16(ACC_, PB_)                                            \
  {                                                                 \
    const float4 a_ = LD4(PB_);                                     \
    const float4 b_ = LD4((PB_) + 4);                               \
    const float4 c_ = LD4((PB_) + 8);                               \
    const float4 d_ = LD4((PB_) + 12);                              \
    ACC_[0] = a_.x; ACC_[1] = a_.y; ACC_[2] = a_.z; ACC_[3] = a_.w; \
    ACC_[4] = b_.x; ACC_[5] = b_.y; ACC_[6] = b_.z; ACC_[7] = b_.w; \
    ACC_[8] = c_.x; ACC_[9] = c_.y; ACC_[10] = c_.z; ACC_[11] = c_.w; \
    ACC_[12] = d_.x; ACC_[13] = d_.y; ACC_[14] = d_.z; ACC_[15] = d_.w; \
  }

// ---------------------------------------------------------------------------
// f32 DPP max step (round-8): value-only wave max. Replaces the u64
// (value,index) DPP chain: 2 instr/step (dpp mov + v_max_f32) instead of
// ~5 dependent ones. Masked-out rows keep self -> fmax no-op.
// ---------------------------------------------------------------------------
template <int CTRL, int RMASK>
__device__ __forceinline__ float dpp_max_f32(float v) {
  int m = __builtin_amdgcn_update_dpp(__float_as_int(v), __float_as_int(v),
                                      CTRL, RMASK, 0xF, false);
  return fmaxf(v, __int_as_float(m));
}

// ---------------------------------------------------------------------------
// Kernel A (round-8, fused): block 0 = FPS; blocks 1..128 = GT precompute
// (depends only on features/W1/b1, so it hides entirely under FPS on the
// other 255 CUs).
//
// FPS restructure: separate value-max from index recovery.
//  - per-thread: fmin update (source-identical arithmetic), then a depth-4
//    fmaxf TREE (was: 16-deep sequential cmp/cndmask argmax chain),
//  - wave: 6-step f32 DPP max (was u64 -> ~3x shorter dependency chain),
//  - block: 8-float LDS max; only threads with bm==bmax scan their 16
//    mind[] for the first match (compile-time indices -> stays in VGPRs)
//    and atomicMin the point index (exact jnp.argmax first-index ties),
//  - the winning thread broadcasts the next center's coords THROUGH LDS
//    from its registers -> removes the dependent global s_load (~300 cyc)
//    from the per-iteration critical path, at the cost of a 3rd barrier.
// ---------------------------------------------------------------------------
#define FPS_T 512
#define FPS_P (N_POINTS / FPS_T)  // 16

__global__ __launch_bounds__(FPS_T) void fps_gt_kernel(
    const float* __restrict__ coords, float* __restrict__ out_centers,
    const float* __restrict__ features, const float* __restrict__ W1,
    const float* __restrict__ b1, float* __restrict__ GT) {
  const int tid = threadIdx.x;

  if (blockIdx.x != 0) {
    // ---- GT precompute (feature half of L1), transposed through LDS ----
    __shared__ float w[IFD * L1D];   // 16 KB
    __shared__ float tile[64 * 65];  // 16.25 KB, padded leading dim
    const int bk = blockIdx.x - 1;
    const int n0 = bk * 64;
    for (int s = tid; s < IFD * L1D; s += FPS_T) w[s] = W1[3 * L1D + s];
    __syncthreads();
    const int j = tid & 63;
    const int nl = tid >> 6;  // 0..7
    const float bj = b1[j];
#pragma unroll 1
    for (int itn = 0; itn < 8; itn++) {
      const int nn = nl + itn * 8;  // 0..63
      const float* __restrict__ frow = features + (size_t)(n0 + nn) * IFD;
      float acc = bj;
#pragma unroll 16
      for (int i = 0; i < IFD; i++) acc = fmaf(frow[i], w[i * 64 + j], acc);
      tile[j * 65 + nn] = acc;
    }
    __syncthreads();
    const int t = tid & 63;
#pragma unroll 1
    for (int jr = tid >> 6; jr < 64; jr += 8)
      GT[(size_t)jr * N_POINTS + n0 + t] = tile[jr * 65 + t];  // coalesced
    return;
  }

  // ---- FPS (block 0, single CU) ----
  __shared__ float wmax[2][FPS_T / 64];
  __shared__ int widx_s[2];
  __shared__ float cxyz[2][4];
  const int lane = tid & 63;

  float px[FPS_P], py[FPS_P], pz[FPS_P], mind[FPS_P];
#pragma unroll
  for (int i = 0; i < FPS_P; i++) {
    int n = tid + i * FPS_T;
    px[i] = coords[3 * n];
    py[i] = coords[3 * n + 1];
    pz[i] = coords[3 * n + 2];
    mind[i] = 1e10f;
  }
  if (tid == 0) {
    float c0 = coords[0], c1 = coords[1], c2 = coords[2];
    out_centers[0] = c0; out_centers[1] = c1; out_centers[2] = c2;
    cxyz[0][0] = c0; cxyz[0][1] = c1; cxyz[0][2] = c2;
  }

  for (int it = 1; it < K_CENTERS; it++) {
    const int buf = it & 1;
    __syncthreads();  // A: cxyz[buf^1] from previous iteration visible
    const float cx = cxyz[buf ^ 1][0];
    const float cy = cxyz[buf ^ 1][1];
    const float cz = cxyz[buf ^ 1][2];
#pragma unroll
    for (int i = 0; i < FPS_P; i++) {
      float dx = px[i] - cx, dy = py[i] - cy, dz = pz[i] - cz;
      float d2 = dx * dx + dy * dy + dz * dz;  // exact expr of passing rounds
      mind[i] = fminf(mind[i], d2);
    }
    // depth-4 max tree (breaks the old 16-deep sequential argmax chain)
    float t8[8];
#pragma unroll
    for (int i = 0; i < 8; i++) t8[i] = fmaxf(mind[i], mind[i + 8]);
#pragma unroll
    for (int i = 0; i < 4; i++) t8[i] = fmaxf(t8[i], t8[i + 4]);
    const float bm = fmaxf(fmaxf(t8[0], t8[1]), fmaxf(t8[2], t8[3]));

    float wm = bm;
    wm = dpp_max_f32<0xB1, 0xF>(wm);   // quad_perm [1,0,3,2]  (xor 1)
    wm = dpp_max_f32<0x4E, 0xF>(wm);   // quad_perm [2,3,0,1]  (xor 2)
    wm = dpp_max_f32<0x141, 0xF>(wm);  // row_half_mirror      (xor 7)
    wm = dpp_max_f32<0x140, 0xF>(wm);  // row_mirror           (xor 15)
    wm = dpp_max_f32<0x142, 0xA>(wm);  // bcast15 -> rows 1,3
    wm = dpp_max_f32<0x143, 0xC>(wm);  // bcast31 -> rows 2,3; lane63 = max
    if (lane == 63) wmax[buf][tid >> 6] = wm;
    if (tid == 0) widx_s[buf] = 0x7FFFFFFF;  // reset guarded by A..B window
    __syncthreads();  // B

    float bmax = wmax[buf][0];
#pragma unroll
    for (int w2 = 1; w2 < FPS_T / 64; w2++) bmax = fmaxf(bmax, wmax[buf][w2]);

    bool found = false;
    int myn = 0;
    float ox = 0.0f, oy = 0.0f, oz = 0.0f;
    if (bm == bmax) {  // only the winning thread(s) scan (usually one)
#pragma unroll
      for (int i = 0; i < FPS_P; i++) {
        if (!found && mind[i] == bmax) {  // i compile-time -> regs, no spill
          found = true;
          myn = tid + i * FPS_T;  // ascending i -> first (smallest) index
          ox = px[i]; oy = py[i]; oz = pz[i];
        }
      }
      atomicMin(&widx_s[buf], myn);  // exact first-max-index tie semantics
    }
    __syncthreads();  // C: widx_s final

    if (found && myn == widx_s[buf]) {  // unique owner broadcasts center
      cxyz[buf][0] = ox; cxyz[buf][1] = oy; cxyz[buf][2] = oz;
      out_centers[3 * it] = ox;
      out_centers[3 * it + 1] = oy;
      out_centers[3 * it + 2] = oz;
    }
  }
}

// ---------------------------------------------------------------------------
// Kernel B: ball query only (GT half moved into the FPS launch). Unchanged
// logic otherwise.
// ---------------------------------------------------------------------------
__global__ __launch_bounds__(256) void prep_kernel(
    const float* __restrict__ coords, const float* __restrict__ centers,
    int* __restrict__ counts, int* __restrict__ Q,
    float* __restrict__ out_feat) {
  __shared__ int q[QS];
  __shared__ int qc;
  const int tid = threadIdx.x;
  const int k = blockIdx.x;
  if (tid < L3D) out_feat[k * L3D + tid] = 0.0f;  // relu>=0, ball non-empty
  if (tid == 0) qc = 0;
  const float cx = centers[3 * k], cy = centers[3 * k + 1],
              cz = centers[3 * k + 2];
  __syncthreads();
#pragma unroll
  for (int s = 0; s < N_POINTS / 256; s++) {
    const int n = s * 256 + tid;
    float dx = coords[3 * n] - cx;
    float dy = coords[3 * n + 1] - cy;
    float dz = coords[3 * n + 2] - cz;
    float d2 = dx * dx + dy * dy + dz * dz;
    if (sqrtf(d2) < 1.0f) {  // match reference: norm(rel) < RADIUS
      int p = atomicAdd(&qc, 1);
      if (p < QS) q[p] = n;
    }
  }
  __syncthreads();
  int M = qc;
  if (M > QS) M = QS;
  if (tid == 0) counts[k] = M;
  for (int i = tid; i < M; i += 256) Q[k * QS + i] = q[i];
}

// ---------------------------------------------------------------------------
// Kernel C: balanced MLP + masked max, LANE = POINT layout. UNCHANGED
// (isolating the FPS change this round; mlp counters next round).
// ---------------------------------------------------------------------------
__global__ __launch_bounds__(256) void mlp_kernel(
    const float* __restrict__ coords, const float* __restrict__ GT,
    const float* __restrict__ W1, const float* __restrict__ W2,
    const float* __restrict__ b2, const float* __restrict__ W3,
    const float* __restrict__ b3, const float* __restrict__ centers,
    const int* __restrict__ counts, const int* __restrict__ Q,
    float* __restrict__ out_feat) {
  __shared__ float hbuf[256 * 64];  // 64 KB: per-thread 64-float scratch
  const int tid = threadIdx.x;
  const int lane = tid & 63;
  float* __restrict__ hrow = hbuf + tid * 64;
  const int gwave = (blockIdx.x * 256 + tid) >> 6;
  const int nwaves = (gridDim.x * 256) >> 6;

  // per-wave chunk prefix over centers: P_k = ceil(counts[k]/64)
  int s0 = (counts[lane] + 63) >> 6;
  int s1 = (counts[64 + lane] + 63) >> 6;
#pragma unroll
  for (int off = 1; off < 64; off <<= 1) {
    int t0 = __shfl_up(s0, off, 64);
    int t1 = __shfl_up(s1, off, 64);
    if (lane >= off) { s0 += t0; s1 += t1; }
  }
  s1 += __shfl(s0, 63, 64);
  const int C = __shfl(s1, 63, 64);  // total chunks
  const int p1 = s0;                 // prefix[lane+1]
  const int p65 = s1;                // prefix[lane+65]

  for (int c = gwave; c < C; c += nwaves) {
    int k = __popcll(__ballot(p1 <= c)) + __popcll(__ballot(p65 <= c));
    k = __builtin_amdgcn_readfirstlane(k);
    int pk = 0;
    if (k > 0)
      pk = (k <= 64) ? __shfl(s0, k - 1, 64) : __shfl(s1, k - 65, 64);
    const int Mk = counts[k];
    int m = (c - pk) * 64 + lane;
    if (m >= Mk) m = Mk - 1;  // pad with a real point; duplicate ok for max
    const int n = Q[(k << 12) + m];

    const float cx = centers[3 * k], cy = centers[3 * k + 1],
                cz = centers[3 * k + 2];
    const float dx = coords[3 * n] - cx;
    const float dy = coords[3 * n + 1] - cy;
    const float dz = coords[3 * n + 2] - cz;

    // ---- fused L1+L2: h2[jg*16+t], 4 groups; h1 recomputed per group ----
#pragma unroll 1
    for (int jg = 0; jg < 4; jg++) {
      vf16 acc;
      SET16(acc, b2 + jg * 16)
#pragma unroll 1
      for (int i = 0; i < 64; i += 4) {
        const float g0 = GT[(i + 0) * N_POINTS + n];  // coalesced (lane = n)
        const float g1 = GT[(i + 1) * N_POINTS + n];
        const float g2 = GT[(i + 2) * N_POINTS + n];
        const float g3 = GT[(i + 3) * N_POINTS + n];
        const float e0 = fmaxf(
            fmaf(dz, W1[128 + i], fmaf(dy, W1[64 + i], fmaf(dx, W1[i], g0))),
            0.0f);
        const float e1 = fmaxf(
            fmaf(dz, W1[129 + i],
                 fmaf(dy, W1[65 + i], fmaf(dx, W1[i + 1], g1))),
            0.0f);
        const float e2 = fmaxf(
            fmaf(dz, W1[130 + i],
                 fmaf(dy, W1[66 + i], fmaf(dx, W1[i + 2], g2))),
            0.0f);
        const float e3 = fmaxf(
            fmaf(dz, W1[131 + i],
                 fmaf(dy, W1[67 + i], fmaf(dx, W1[i + 3], g3))),
            0.0f);
        const float* __restrict__ w2r = W2 + i * 64 + jg * 16;  // uniform
        FMA16ROW(acc, w2r, e0)
        FMA16ROW(acc, w2r + 64, e1)
        FMA16ROW(acc, w2r + 128, e2)
        FMA16ROW(acc, w2r + 192, e3)
      }
#pragma unroll
      for (int t = 0; t < 16; t++)
        hrow[(jg * 16 + t + lane) & 63] = fmaxf(acc[t], 0.0f);
    }

    // ---- L3: 8 groups of 16 channels; h2 read back from LDS ----
#pragma unroll 1
    for (int jg = 0; jg < 8; jg++) {
      vf16 acc;
      SET16(acc, b3 + jg * 16)
#pragma unroll 1
      for (int i = 0; i < 64; i += 4) {
        const float e0 = hrow[(i + 0 + lane) & 63];
        const float e1 = hrow[(i + 1 + lane) & 63];
        const float e2 = hrow[(i + 2 + lane) & 63];
        const float e3 = hrow[(i + 3 + lane) & 63];
        const float* __restrict__ w3r = W3 + i * L3D + jg * 16;  // uniform
        FMA16ROW(acc, w3r, e0)
        FMA16ROW(acc, w3r + 128, e1)
        FMA16ROW(acc, w3r + 256, e2)
        FMA16ROW(acc, w3r + 384, e3)
      }
#pragma unroll
      for (int t = 0; t < 16; t++) {
        float v = fmaxf(acc[t], 0.0f);
#pragma unroll
        for (int off = 32; off >= 1; off >>= 1)
          v = fmaxf(v, __shfl_xor(v, off, 64));
        if (lane == 0)
          atomicMax((unsigned int*)&out_feat[k * L3D + jg * 16 + t],
                    __float_as_uint(v));
      }
    }
  }
}

// ---------------------------------------------------------------------------
extern "C" void kernel_launch(void* const* d_in, const int* in_sizes, int n_in,
                              void* d_out, int out_size, void* d_ws,
                              size_t ws_size, hipStream_t stream) {
  const float* coords = (const float*)d_in[0];    // [8192,3]
  const float* features = (const float*)d_in[1];  // [8192,64]
  const float* W1 = (const float*)d_in[2];        // [67,64]
  const float* b1 = (const float*)d_in[3];        // [64]
  const float* W2 = (const float*)d_in[4];        // [64,64]
  const float* b2 = (const float*)d_in[5];        // [64]
  const float* W3 = (const float*)d_in[6];        // [64,128]
  const float* b3 = (const float*)d_in[7];        // [128]

  float* out = (float*)d_out;
  float* centers = out;                   // [128*3]
  float* out_feat = out + K_CENTERS * 3;  // [128*128]

  char* ws = (char*)d_ws;
  float* GT = (float*)ws;                            // 2 MB, [64][8192]
  int* Q = (int*)(ws + (size_t)N_POINTS * L1D * 4);  // 2 MB
  int* counts = (int*)(ws + 4 * 1024 * 1024);        // 512 B

  fps_gt_kernel<<<1 + K_CENTERS, FPS_T, 0, stream>>>(coords, centers,
                                                     features, W1, b1, GT);
  prep_kernel<<<K_CENTERS, 256, 0, stream>>>(coords, centers, counts, Q,
                                             out_feat);
  mlp_kernel<<<256, 256, 0, stream>>>(coords, GT, W1, W2, b2, W3, b3, centers,
                                      counts, Q, out_feat);
}

// Round 2
// 308.952 us; speedup vs baseline: 1.1468x; 1.1468x over previous
//
#include <hip/hip_runtime.h>

#define N_POINTS 8192
#define K_CENTERS 128
#define IFD 64
#define L1D 64
#define L2D 64
#define L3D 128
#define QS 4096  // max points per ball (observed max ~1.7K for N(0,1) coords)

typedef float vf16 __attribute__((ext_vector_type(16)));

#define LD4(p) (*(const float4*)(p))
// Param names must not collide with .x/.y/.z/.w member tokens.
#define FMA4(D_, O_, W_, V_)                       \
  D_[(O_) + 0] = fmaf(V_, (W_).x, D_[(O_) + 0]);   \
  D_[(O_) + 1] = fmaf(V_, (W_).y, D_[(O_) + 1]);   \
  D_[(O_) + 2] = fmaf(V_, (W_).z, D_[(O_) + 2]);   \
  D_[(O_) + 3] = fmaf(V_, (W_).w, D_[(O_) + 3]);

#define FMA16ROW(ACC_, PW_, HV_)                                    \
  {                                                                 \
    const float4 wa_ = LD4(PW_);                                    \
    const float4 wb_ = LD4((PW_) + 4);                              \
    const float4 wc_ = LD4((PW_) + 8);                              \
    const float4 wd_ = LD4((PW_) + 12);                             \
    FMA4(ACC_, 0, wa_, HV_)                                         \
    FMA4(ACC_, 4, wb_, HV_)                                         \
    FMA4(ACC_, 8, wc_, HV_)                                         \
    FMA4(ACC_, 12, wd_, HV_)                                        \
  }

#define SET16(ACC_, PB_)                                            \
  {                                                                 \
    const float4 a_ = LD4(PB_);                                     \
    const float4 b_ = LD4((PB_) + 4);                               \
    const float4 c_ = LD4((PB_) + 8);                               \
    const float4 d_ = LD4((PB_) + 12);                              \
    ACC_[0] = a_.x; ACC_[1] = a_.y; ACC_[2] = a_.z; ACC_[3] = a_.w; \
    ACC_[4] = b_.x; ACC_[5] = b_.y; ACC_[6] = b_.z; ACC_[7] = b_.w; \
    ACC_[8] = c_.x; ACC_[9] = c_.y; ACC_[10] = c_.z; ACC_[11] = c_.w; \
    ACC_[12] = d_.x; ACC_[13] = d_.y; ACC_[14] = d_.z; ACC_[15] = d_.w; \
  }

// ---------------------------------------------------------------------------
// DPP u64-max step: partner = DPP-permuted (hi,lo); keep the larger key.
// ---------------------------------------------------------------------------
template <int CTRL, int RMASK>
__device__ __forceinline__ void dpp_max_u64(unsigned& hi, unsigned& lo) {
  unsigned h2 = (unsigned)__builtin_amdgcn_update_dpp(
      (int)hi, (int)hi, CTRL, RMASK, 0xF, false);
  unsigned l2 = (unsigned)__builtin_amdgcn_update_dpp(
      (int)lo, (int)lo, CTRL, RMASK, 0xF, false);
  unsigned long long a = ((unsigned long long)hi << 32) | lo;
  unsigned long long b = ((unsigned long long)h2 << 32) | l2;
  if (b > a) { hi = h2; lo = l2; }
}

// ---------------------------------------------------------------------------
// Kernel A (round-9): block 0 = FPS; blocks 1..128 = GT precompute (hidden
// under FPS on the other CUs).
//
// FPS post-mortem of round 8: the 3-barrier structure cost ~865 cyc/iter
// (barriers on an 8-wave block are ~300-400 cyc each) — more than the
// removed s_load. Round-9 structure = ONE barrier per iteration:
//  - per-thread (value,index) via depth-4 TREES (fmax tree + 16 parallel
//    cndmask + min-tree) instead of the 16-deep serial argmax chain,
//  - packed u64 (value,N-1-idx) DPP wave max  -> lane 63 (index rides along,
//    no recovery pass, no atomicMin, no extra barriers),
//  - double-buffered wmax, single barrier, depth-3 u64 block tree,
//  - coords mirrored in LDS (96 KB): winner fetch = 3 broadcast ds_read_b32
//    (~120 cyc, no barrier needed — region is read-only after init) instead
//    of the dependent scalar L2 load (~250-500 cyc).
// ---------------------------------------------------------------------------
#define FPS_T 512
#define FPS_P (N_POINTS / FPS_T)  // 16

// LDS overlay: fps branch needs 96 KB coords + 128 B wmax; GT branch needs
// 16 KB W + 16.9 KB tile. Union both in one char buffer (gfx950 allows
// >64 KB static LDS; 160 KB/CU).
#define SMEM_BYTES (98304 + 128)

__global__ __launch_bounds__(FPS_T) void fps_gt_kernel(
    const float* __restrict__ coords, float* __restrict__ out_centers,
    const float* __restrict__ features, const float* __restrict__ W1,
    const float* __restrict__ b1, float* __restrict__ GT) {
  __shared__ __align__(16) char smem[SMEM_BYTES];
  const int tid = threadIdx.x;

  if (blockIdx.x != 0) {
    // ---- GT precompute (feature half of L1), transposed through LDS ----
    float* w = (float*)smem;             // 16 KB
    float* tile = (float*)(smem + 16384);  // 64*65*4 = 16.9 KB
    const int bk = blockIdx.x - 1;
    const int n0 = bk * 64;
    for (int s = tid; s < IFD * L1D; s += FPS_T) w[s] = W1[3 * L1D + s];
    __syncthreads();
    const int j = tid & 63;
    const int nl = tid >> 6;  // 0..7
    const float bj = b1[j];
#pragma unroll 1
    for (int itn = 0; itn < 8; itn++) {
      const int nn = nl + itn * 8;  // 0..63
      const float* __restrict__ frow = features + (size_t)(n0 + nn) * IFD;
      float acc = bj;
#pragma unroll 16
      for (int i = 0; i < IFD; i++) acc = fmaf(frow[i], w[i * 64 + j], acc);
      tile[j * 65 + nn] = acc;
    }
    __syncthreads();
    const int t = tid & 63;
#pragma unroll 1
    for (int jr = tid >> 6; jr < 64; jr += 8)
      GT[(size_t)jr * N_POINTS + n0 + t] = tile[jr * 65 + t];  // coalesced
    return;
  }

  // ---- FPS (block 0, single CU) ----
  float* clds = (float*)smem;  // [8192][3] mirror of coords
  unsigned long long* wmax = (unsigned long long*)(smem + 98304);  // [2][8]
  const int lane = tid & 63;
  const int wid = tid >> 6;

  // coords -> LDS, float4-wide (6144 float4 / 512 thr = 12 each)
  {
    const float4* __restrict__ src = (const float4*)coords;
    float4* dst = (float4*)smem;
#pragma unroll
    for (int i = 0; i < 12; i++) dst[tid + i * FPS_T] = src[tid + i * FPS_T];
  }

  float px[FPS_P], py[FPS_P], pz[FPS_P], mind[FPS_P];
#pragma unroll
  for (int i = 0; i < FPS_P; i++) {
    int n = tid + i * FPS_T;
    px[i] = coords[3 * n];
    py[i] = coords[3 * n + 1];
    pz[i] = coords[3 * n + 2];
    mind[i] = 1e10f;
  }

  float cx = coords[0], cy = coords[1], cz = coords[2];
  if (tid == 0) {
    out_centers[0] = cx; out_centers[1] = cy; out_centers[2] = cz;
  }
  __syncthreads();  // LDS coords mirror complete

  for (int it = 1; it < K_CENTERS; it++) {
#pragma unroll
    for (int i = 0; i < FPS_P; i++) {
      float dx = px[i] - cx, dy = py[i] - cy, dz = pz[i] - cz;
      float d2 = dx * dx + dy * dy + dz * dz;  // exact expr of passing rounds
      mind[i] = fminf(mind[i], d2);
    }
    // value: depth-4 fmax tree
    float t8[8];
#pragma unroll
    for (int i = 0; i < 8; i++) t8[i] = fmaxf(mind[i], mind[i + 8]);
#pragma unroll
    for (int i = 0; i < 4; i++) t8[i] = fmaxf(t8[i], t8[i + 4]);
    const float bm = fmaxf(fmaxf(t8[0], t8[1]), fmaxf(t8[2], t8[3]));
    // index: 16 parallel cndmask + depth-4 min tree (first match = min idx)
    int cand[FPS_P];
#pragma unroll
    for (int i = 0; i < FPS_P; i++)
      cand[i] = (mind[i] == bm) ? (tid + i * FPS_T) : 0x7FFFFFFF;
#pragma unroll
    for (int s = 8; s > 0; s >>= 1)
#pragma unroll
      for (int i = 0; i < s; i++) cand[i] = min(cand[i], cand[i + s]);

    unsigned hi = __float_as_uint(bm);                  // bm >= 0
    unsigned lo = (unsigned)(N_POINTS - 1 - cand[0]);   // max -> min index
    dpp_max_u64<0xB1, 0xF>(hi, lo);   // quad_perm [1,0,3,2]  (xor 1)
    dpp_max_u64<0x4E, 0xF>(hi, lo);   // quad_perm [2,3,0,1]  (xor 2)
    dpp_max_u64<0x141, 0xF>(hi, lo);  // row_half_mirror      (xor 7)
    dpp_max_u64<0x140, 0xF>(hi, lo);  // row_mirror           (xor 15)
    dpp_max_u64<0x142, 0xA>(hi, lo);  // bcast15 -> rows 1,3
    dpp_max_u64<0x143, 0xC>(hi, lo);  // bcast31 -> rows 2,3; lane63 = max
    const int buf = it & 1;
    if (lane == 63)
      wmax[(buf << 3) + wid] = ((unsigned long long)hi << 32) | lo;
    __syncthreads();  // double-buffered: one barrier per iteration is safe

    const unsigned long long* __restrict__ wb = wmax + (buf << 3);
    unsigned long long a0 = wb[0], a1 = wb[1], a2 = wb[2], a3 = wb[3];
    unsigned long long a4 = wb[4], a5 = wb[5], a6 = wb[6], a7 = wb[7];
    a0 = a0 > a4 ? a0 : a4;
    a1 = a1 > a5 ? a1 : a5;
    a2 = a2 > a6 ? a2 : a6;
    a3 = a3 > a7 ? a3 : a7;
    a0 = a0 > a2 ? a0 : a2;
    a1 = a1 > a3 ? a1 : a3;
    a0 = a0 > a1 ? a0 : a1;
    const int widx = N_POINTS - 1 - (int)(a0 & 0xFFFFFFFFull);
    cx = clds[widx * 3];          // broadcast ds_read, no barrier needed
    cy = clds[widx * 3 + 1];
    cz = clds[widx * 3 + 2];
    if (tid == 0) {
      out_centers[3 * it] = cx;
      out_centers[3 * it + 1] = cy;
      out_centers[3 * it + 2] = cz;
    }
  }
}

// ---------------------------------------------------------------------------
// Kernel B: ball query only. Unchanged from round 8.
// ---------------------------------------------------------------------------
__global__ __launch_bounds__(256) void prep_kernel(
    const float* __restrict__ coords, const float* __restrict__ centers,
    int* __restrict__ counts, int* __restrict__ Q,
    float* __restrict__ out_feat) {
  __shared__ int q[QS];
  __shared__ int qc;
  const int tid = threadIdx.x;
  const int k = blockIdx.x;
  if (tid < L3D) out_feat[k * L3D + tid] = 0.0f;  // relu>=0, ball non-empty
  if (tid == 0) qc = 0;
  const float cx = centers[3 * k], cy = centers[3 * k + 1],
              cz = centers[3 * k + 2];
  __syncthreads();
#pragma unroll
  for (int s = 0; s < N_POINTS / 256; s++) {
    const int n = s * 256 + tid;
    float dx = coords[3 * n] - cx;
    float dy = coords[3 * n + 1] - cy;
    float dz = coords[3 * n + 2] - cz;
    float d2 = dx * dx + dy * dy + dz * dz;
    if (sqrtf(d2) < 1.0f) {  // match reference: norm(rel) < RADIUS
      int p = atomicAdd(&qc, 1);
      if (p < QS) q[p] = n;
    }
  }
  __syncthreads();
  int M = qc;
  if (M > QS) M = QS;
  if (tid == 0) counts[k] = M;
  for (int i = tid; i < M; i += 256) Q[k * QS + i] = q[i];
}

// ---------------------------------------------------------------------------
// Kernel C: balanced MLP + masked max, LANE = POINT layout. UNCHANGED.
// ---------------------------------------------------------------------------
__global__ __launch_bounds__(256) void mlp_kernel(
    const float* __restrict__ coords, const float* __restrict__ GT,
    const float* __restrict__ W1, const float* __restrict__ W2,
    const float* __restrict__ b2, const float* __restrict__ W3,
    const float* __restrict__ b3, const float* __restrict__ centers,
    const int* __restrict__ counts, const int* __restrict__ Q,
    float* __restrict__ out_feat) {
  __shared__ float hbuf[256 * 64];  // 64 KB: per-thread 64-float scratch
  const int tid = threadIdx.x;
  const int lane = tid & 63;
  float* __restrict__ hrow = hbuf + tid * 64;
  const int gwave = (blockIdx.x * 256 + tid) >> 6;
  const int nwaves = (gridDim.x * 256) >> 6;

  // per-wave chunk prefix over centers: P_k = ceil(counts[k]/64)
  int s0 = (counts[lane] + 63) >> 6;
  int s1 = (counts[64 + lane] + 63) >> 6;
#pragma unroll
  for (int off = 1; off < 64; off <<= 1) {
    int t0 = __shfl_up(s0, off, 64);
    int t1 = __shfl_up(s1, off, 64);
    if (lane >= off) { s0 += t0; s1 += t1; }
  }
  s1 += __shfl(s0, 63, 64);
  const int C = __shfl(s1, 63, 64);  // total chunks
  const int p1 = s0;                 // prefix[lane+1]
  const int p65 = s1;                // prefix[lane+65]

  for (int c = gwave; c < C; c += nwaves) {
    int k = __popcll(__ballot(p1 <= c)) + __popcll(__ballot(p65 <= c));
    k = __builtin_amdgcn_readfirstlane(k);
    int pk = 0;
    if (k > 0)
      pk = (k <= 64) ? __shfl(s0, k - 1, 64) : __shfl(s1, k - 65, 64);
    const int Mk = counts[k];
    int m = (c - pk) * 64 + lane;
    if (m >= Mk) m = Mk - 1;  // pad with a real point; duplicate ok for max
    const int n = Q[(k << 12) + m];

    const float cx = centers[3 * k], cy = centers[3 * k + 1],
                cz = centers[3 * k + 2];
    const float dx = coords[3 * n] - cx;
    const float dy = coords[3 * n + 1] - cy;
    const float dz = coords[3 * n + 2] - cz;

    // ---- fused L1+L2: h2[jg*16+t], 4 groups; h1 recomputed per group ----
#pragma unroll 1
    for (int jg = 0; jg < 4; jg++) {
      vf16 acc;
      SET16(acc, b2 + jg * 16)
#pragma unroll 1
      for (int i = 0; i < 64; i += 4) {
        const float g0 = GT[(i + 0) * N_POINTS + n];  // coalesced (lane = n)
        const float g1 = GT[(i + 1) * N_POINTS + n];
        const float g2 = GT[(i + 2) * N_POINTS + n];
        const float g3 = GT[(i + 3) * N_POINTS + n];
        const float e0 = fmaxf(
            fmaf(dz, W1[128 + i], fmaf(dy, W1[64 + i], fmaf(dx, W1[i], g0))),
            0.0f);
        const float e1 = fmaxf(
            fmaf(dz, W1[129 + i],
                 fmaf(dy, W1[65 + i], fmaf(dx, W1[i + 1], g1))),
            0.0f);
        const float e2 = fmaxf(
            fmaf(dz, W1[130 + i],
                 fmaf(dy, W1[66 + i], fmaf(dx, W1[i + 2], g2))),
            0.0f);
        const float e3 = fmaxf(
            fmaf(dz, W1[131 + i],
                 fmaf(dy, W1[67 + i], fmaf(dx, W1[i + 3], g3))),
            0.0f);
        const float* __restrict__ w2r = W2 + i * 64 + jg * 16;  // uniform
        FMA16ROW(acc, w2r, e0)
        FMA16ROW(acc, w2r + 64, e1)
        FMA16ROW(acc, w2r + 128, e2)
        FMA16ROW(acc, w2r + 192, e3)
      }
#pragma unroll
      for (int t = 0; t < 16; t++)
        hrow[(jg * 16 + t + lane) & 63] = fmaxf(acc[t], 0.0f);
    }

    // ---- L3: 8 groups of 16 channels; h2 read back from LDS ----
#pragma unroll 1
    for (int jg = 0; jg < 8; jg++) {
      vf16 acc;
      SET16(acc, b3 + jg * 16)
#pragma unroll 1
      for (int i = 0; i < 64; i += 4) {
        const float e0 = hrow[(i + 0 + lane) & 63];
        const float e1 = hrow[(i + 1 + lane) & 63];
        const float e2 = hrow[(i + 2 + lane) & 63];
        const float e3 = hrow[(i + 3 + lane) & 63];
        const float* __restrict__ w3r = W3 + i * L3D + jg * 16;  // uniform
        FMA16ROW(acc, w3r, e0)
        FMA16ROW(acc, w3r + 128, e1)
        FMA16ROW(acc, w3r + 256, e2)
        FMA16ROW(acc, w3r + 384, e3)
      }
#pragma unroll
      for (int t = 0; t < 16; t++) {
        float v = fmaxf(acc[t], 0.0f);
#pragma unroll
        for (int off = 32; off >= 1; off >>= 1)
          v = fmaxf(v, __shfl_xor(v, off, 64));
        if (lane == 0)
          atomicMax((unsigned int*)&out_feat[k * L3D + jg * 16 + t],
                    __float_as_uint(v));
      }
    }
  }
}

// ---------------------------------------------------------------------------
extern "C" void kernel_launch(void* const* d_in, const int* in_sizes, int n_in,
                              void* d_out, int out_size, void* d_ws,
                              size_t ws_size, hipStream_t stream) {
  const float* coords = (const float*)d_in[0];    // [8192,3]
  const float* features = (const float*)d_in[1];  // [8192,64]
  const float* W1 = (const float*)d_in[2];        // [67,64]
  const float* b1 = (const float*)d_in[3];        // [64]
  const float* W2 = (const float*)d_in[4];        // [64,64]
  const float* b2 = (const float*)d_in[5];        // [64]
  const float* W3 = (const float*)d_in[6];        // [64,128]
  const float* b3 = (const float*)d_in[7];        // [128]

  float* out = (float*)d_out;
  float* centers = out;                   // [128*3]
  float* out_feat = out + K_CENTERS * 3;  // [128*128]

  char* ws = (char*)d_ws;
  float* GT = (float*)ws;                            // 2 MB, [64][8192]
  int* Q = (int*)(ws + (size_t)N_POINTS * L1D * 4);  // 2 MB
  int* counts = (int*)(ws + 4 * 1024 * 1024);        // 512 B

  fps_gt_kernel<<<1 + K_CENTERS, FPS_T, 0, stream>>>(coords, centers,
                                                     features, W1, b1, GT);
  prep_kernel<<<K_CENTERS, 256, 0, stream>>>(coords, centers, counts, Q,
                                             out_feat);
  mlp_kernel<<<256, 256, 0, stream>>>(coords, GT, W1, W2, b2, W3, b3, centers,
                                      counts, Q, out_feat);
}